// Round 3
// baseline (249.366 us; speedup 1.0000x reference)
//
#include <hip/hip_runtime.h>
#include <stdint.h>

// HyperLatticeBlock: B=2,S=1024,D=1024,L=48,K=4  (tokens T=2048)
// gate(top4)->Wconv-transpose(bf16)->bucketed expert GEMM(gll+swizzle)->combine->out_proj->LN
#define TT 2048
#define DD 1024
#define LL 48

typedef __attribute__((ext_vector_type(8))) short short8;
typedef __attribute__((ext_vector_type(4))) float f32x4;

static __device__ __forceinline__ unsigned int f2bf(float f) {
  union { float f; unsigned int u; } v; v.f = f;
  return (v.u + 0x7FFFu + ((v.u >> 16) & 1u)) >> 16;   // RNE f32->bf16 bits
}
static __device__ __forceinline__ unsigned int pack2(float a, float b) {
  return f2bf(a) | (f2bf(b) << 16);
}

typedef __attribute__((address_space(1))) const void* as1_t;
typedef __attribute__((address_space(3))) void* as3_t;
static __device__ __forceinline__ void gll16(const void* g, void* s) {
  __builtin_amdgcn_global_load_lds((as1_t)g, (as3_t)s, 16, 0, 0);
}

// ---------------- gate: logits fp32, top-4, softmax, bucket scatter, x->bf16 ----------------
__global__ __launch_bounds__(256) void k_gate(
    const float* __restrict__ x, const float* __restrict__ gw,
    unsigned short* __restrict__ xb,
    int* __restrict__ counts, int* __restrict__ btok, float* __restrict__ bscore)
{
  __shared__ float xs[8][1024];
  __shared__ float lg[8][48];
  const int tid = threadIdx.x;
  const int t0 = blockIdx.x * 8;
  for (int u = tid; u < 2048; u += 256) {
    int tok = u >> 8;
    int c = (u & 255) << 2;
    float4 v = *(const float4*)(x + (size_t)(t0 + tok) * DD + c);
    *(float4*)&xs[tok][c] = v;
    uint2 p; p.x = pack2(v.x, v.y); p.y = pack2(v.z, v.w);
    *(uint2*)(xb + (size_t)(t0 + tok) * DD + c) = p;
  }
  __syncthreads();
  const int lane = tid & 63, wid = tid >> 6;
  for (int li = 0; li < 12; ++li) {
    const int l = wid + (li << 2);
    const float4* gp = (const float4*)(gw + (size_t)l * DD);
    float4 g0 = gp[lane], g1 = gp[lane + 64], g2 = gp[lane + 128], g3 = gp[lane + 192];
    for (int tok = 0; tok < 8; ++tok) {
      const float4* xp = (const float4*)&xs[tok][0];
      float4 a0 = xp[lane], a1 = xp[lane + 64], a2 = xp[lane + 128], a3 = xp[lane + 192];
      float s = a0.x*g0.x + a0.y*g0.y + a0.z*g0.z + a0.w*g0.w
              + a1.x*g1.x + a1.y*g1.y + a1.z*g1.z + a1.w*g1.w
              + a2.x*g2.x + a2.y*g2.y + a2.z*g2.z + a2.w*g2.w
              + a3.x*g3.x + a3.y*g3.y + a3.z*g3.z + a3.w*g3.w;
      #pragma unroll
      for (int off = 32; off; off >>= 1) s += __shfl_down(s, off);
      if (lane == 0) lg[tok][l] = s;
    }
  }
  __syncthreads();
  if (tid < 8) {
    const int tok = tid;
    float v[4]; int id[4];
    unsigned long long taken = 0ull;
    for (int k = 0; k < 4; ++k) {
      float best = -3.4e38f; int bi = 0;
      for (int l = 0; l < 48; ++l) {
        float cand = lg[tok][l];
        if (!((taken >> l) & 1ull) && cand > best) { best = cand; bi = l; }
      }
      taken |= (1ull << bi); v[k] = best; id[k] = bi;
    }
    float e1 = expf(v[1] - v[0]);
    float e2 = expf(v[2] - v[0]);
    float e3 = expf(v[3] - v[0]);
    float inv = 1.0f / (1.0f + e1 + e2 + e3);
    float sc[4] = { inv, e1*inv, e2*inv, e3*inv };
    for (int k = 0; k < 4; ++k) {
      int pos = atomicAdd(&counts[id[k]], 1);
      btok[id[k] * TT + pos] = ((t0 + tok) << 2) | k;
      bscore[id[k] * TT + pos] = sc[k];
    }
  }
}

// ---------------- Wconv+transpose: Wt[l][e][d] bf16 <- W[l][d][e] f32, 128x128 tiles ----------------
__global__ __launch_bounds__(256) void k_wconvT(const float* __restrict__ W,
                                                unsigned short* __restrict__ Wt)
{
  const int l = blockIdx.z, d0 = blockIdx.y * 128, e0 = blockIdx.x * 128;
  __shared__ unsigned short T[128][136];   // [e][d], row 272B = 17x16B (aligned b128 slots)
  const float* src = W + (size_t)l * DD * DD;
  const int tid = threadIdx.x;
  #pragma unroll
  for (int i = 0; i < 16; ++i) {
    int fl = i * 256 + tid;          // 4096 float4 = 128 d-rows x 32
    int d = fl >> 5, e4 = fl & 31;
    float4 v = *(const float4*)(src + (size_t)(d0 + d) * DD + e0 + e4 * 4);
    #pragma unroll
    for (int j = 0; j < 4; ++j) {
      int e = e4 * 4 + j;
      int unit = (d >> 3) ^ (e & 7);                    // bank-spread the 16B slots
      float fv = (j == 0) ? v.x : (j == 1) ? v.y : (j == 2) ? v.z : v.w;
      T[e][unit * 8 + (d & 7)] = (unsigned short)f2bf(fv);
    }
  }
  __syncthreads();
  #pragma unroll
  for (int i2 = 0; i2 < 8; ++i2) {
    int uo = i2 * 256 + tid;         // 2048 16B-chunks = 128 e-rows x 16
    int e = uo >> 4, ds = uo & 15;
    short8 s8 = *(const short8*)&T[e][(ds ^ (e & 7)) * 8];
    *(short8*)(Wt + ((size_t)l << 20) + (size_t)(e0 + e) * DD + d0 + ds * 8) = s8;
  }
}

// ---------------- expert GEMM: 128x128 tile, BK=64, global_load_lds + XOR swizzle, dbuf ----------------
// OUT[t][e] = sum_d X[t][d] * Wt[l][e][d]; both operands k(d)-contiguous bf16 rows.
__global__ __launch_bounds__(256) void k_expert(
    const unsigned short* __restrict__ xb, const unsigned short* __restrict__ Wt,
    const int* __restrict__ counts, const int* __restrict__ btok,
    const float* __restrict__ bscore, float* __restrict__ sel)
{
  const int l = blockIdx.z;
  const int ncnt = counts[l];
  const int m0 = blockIdx.y * 128;
  if (m0 >= ncnt) return;
  const int n0 = blockIdx.x * 128;
  const int tid = threadIdx.x, lane = tid & 63, wid = tid >> 6;
  const int wr = wid >> 1, wc = wid & 1;

  __shared__ alignas(16) unsigned short As[2][128][64];   // linear; swizzle via source perm
  __shared__ alignas(16) unsigned short Bs[2][128][64];
  __shared__ int   toks[128];
  __shared__ float scs[128];

  if (tid < 128) {
    int r = m0 + tid;
    toks[tid] = (r < ncnt) ? btok[l * TT + r] : 0;
    scs[tid]  = (r < ncnt) ? bscore[l * TT + r] : 0.f;
  }
  __syncthreads();

  // staging geometry: unit u = i*256+tid (16B units); row r=u>>3 (0..127), phys slot p=u&7.
  // LDS linear; logical k-slot stored at p is p^(r&7)  => pre-swizzled GLOBAL source.
  const int rloc = tid >> 3;                 // + i*32
  const int sl = (tid & 7) ^ (rloc & 7);     // logical slot this lane fetches
  const unsigned short* asrc[4];
  const unsigned short* bsrc[4];
  #pragma unroll
  for (int i = 0; i < 4; ++i) {
    int r = i * 32 + rloc;
    asrc[i] = xb + (size_t)(toks[r] >> 2) * DD + sl * 8;
    bsrc[i] = Wt + ((size_t)l << 20) + (size_t)(n0 + r) * DD + sl * 8;
  }

  f32x4 acc[4][4];
  #pragma unroll
  for (int m = 0; m < 4; ++m)
    #pragma unroll
    for (int n = 0; n < 4; ++n)
      #pragma unroll
      for (int j = 0; j < 4; ++j) acc[m][n][j] = 0.f;

#define STAGE(buf, k0) do { \
    unsigned short* ab = &As[buf][0][0]; \
    unsigned short* bb = &Bs[buf][0][0]; \
    _Pragma("unroll") \
    for (int i = 0; i < 4; ++i) { \
      gll16(asrc[i] + (k0), ab + (i * 256 + tid) * 8); \
      gll16(bsrc[i] + (k0), bb + (i * 256 + tid) * 8); \
    } \
  } while (0)

  const int fr = lane & 15, fq = lane >> 4, fswz = lane & 7;
  const int slotk[2] = { fq ^ fswz, (4 + fq) ^ fswz };   // swizzled slot for kh=0,1

  STAGE(0, 0);
  __syncthreads();
  int cur = 0;
  for (int t = 0; t < 16; ++t) {
    if (t < 15) STAGE(cur ^ 1, (t + 1) * 64);
    const unsigned short* Ab = &As[cur][0][0];
    const unsigned short* Bb = &Bs[cur][0][0];
    #pragma unroll
    for (int kh = 0; kh < 2; ++kh) {
      const int sA = slotk[kh];
      short8 af[4], bf[4];
      #pragma unroll
      for (int m = 0; m < 4; ++m)
        af[m] = *(const short8*)(Ab + ((wr * 64 + m * 16 + fr) << 6) + sA * 8);
      #pragma unroll
      for (int n = 0; n < 4; ++n)
        bf[n] = *(const short8*)(Bb + ((wc * 64 + n * 16 + fr) << 6) + sA * 8);
      #pragma unroll
      for (int m = 0; m < 4; ++m)
        #pragma unroll
        for (int n = 0; n < 4; ++n)
          acc[m][n] = __builtin_amdgcn_mfma_f32_16x16x32_bf16(af[m], bf[n], acc[m][n], 0, 0, 0);
    }
    __syncthreads();
    cur ^= 1;
  }
#undef STAGE

  // epilogue: D[r][c]: c = lane&15 (e), r = (lane>>4)*4 + j  [m89-verified]
  #pragma unroll
  for (int m = 0; m < 4; ++m) {
    #pragma unroll
    for (int j = 0; j < 4; ++j) {
      const int r = wr * 64 + m * 16 + (fq << 2) + j;
      if (m0 + r < ncnt) {
        const float sc = scs[r];
        const size_t ob = (size_t)toks[r] * DD + n0 + wc * 64 + fr;
        #pragma unroll
        for (int n = 0; n < 4; ++n)
          sel[ob + n * 16] = acc[m][n][j] * sc;
      }
    }
  }
}

// ---------------- FALLBACK expert GEMM (round-2, used only if ws too small) ----------------
__global__ __launch_bounds__(256, 2) void k_expert_fb(
    const unsigned short* __restrict__ xb, const float* __restrict__ W,
    const int* __restrict__ counts, const int* __restrict__ btok,
    const float* __restrict__ bscore, float* __restrict__ sel)
{
  const int l = blockIdx.z;
  const int ncnt = counts[l];
  const int m0 = blockIdx.y * 256;
  if (m0 >= ncnt) return;
  const int n0 = blockIdx.x * 64;
  const int tid = threadIdx.x, lane = tid & 63, wid = tid >> 6;

  __shared__ alignas(16) unsigned short As[2][256][40];
  __shared__ alignas(16) unsigned short Bs[2][64][40];
  __shared__ int   toks[256];
  __shared__ float scs[256];

  {
    int r = m0 + tid;
    toks[tid] = (r < ncnt) ? btok[l * TT + r] : 0;
    scs[tid]  = (r < ncnt) ? bscore[l * TT + r] : 0.f;
  }
  __syncthreads();

  const int aq = tid >> 2, aseg = tid & 3;
  const size_t ra0 = (size_t)(toks[aq]       >> 2) * DD + aseg * 8;
  const size_t ra1 = (size_t)(toks[aq + 64]  >> 2) * DD + aseg * 8;
  const size_t ra2 = (size_t)(toks[aq + 128] >> 2) * DD + aseg * 8;
  const size_t ra3 = (size_t)(toks[aq + 192] >> 2) * DD + aseg * 8;
  const int be = tid >> 2, bks = tid & 3;
  const float* wb = W + (size_t)l * DD * DD + (size_t)(bks * 8) * DD + n0 + be;

  f32x4 acc[4][4];
  #pragma unroll
  for (int m = 0; m < 4; ++m)
    #pragma unroll
    for (int n = 0; n < 4; ++n)
      #pragma unroll
      for (int j = 0; j < 4; ++j) acc[m][n][j] = 0.f;

  int4 av0, av1, av2, av3;
  float wv[8];

#define E_LOAD(kk) do { \
    av0 = *(const int4*)(xb + ra0 + (kk)); \
    av1 = *(const int4*)(xb + ra1 + (kk)); \
    av2 = *(const int4*)(xb + ra2 + (kk)); \
    av3 = *(const int4*)(xb + ra3 + (kk)); \
    _Pragma("unroll") \
    for (int j = 0; j < 8; ++j) wv[j] = wb[(size_t)((kk) + j) * DD]; \
  } while (0)

#define E_STORE(b) do { \
    *(int4*)&As[b][aq][aseg * 8]       = av0; \
    *(int4*)&As[b][aq + 64][aseg * 8]  = av1; \
    *(int4*)&As[b][aq + 128][aseg * 8] = av2; \
    *(int4*)&As[b][aq + 192][aseg * 8] = av3; \
    uint4 pv; \
    pv.x = pack2(wv[0], wv[1]); pv.y = pack2(wv[2], wv[3]); \
    pv.z = pack2(wv[4], wv[5]); pv.w = pack2(wv[6], wv[7]); \
    *(uint4*)&Bs[b][be][bks * 8] = pv; \
  } while (0)

  E_LOAD(0); E_STORE(0); __syncthreads();
  int cur = 0;
  for (int t = 0; t < 32; ++t) {
    const bool more = (t < 31);
    if (more) E_LOAD((t + 1) * 32);
    short8 af[4], bf[4];
    #pragma unroll
    for (int n = 0; n < 4; ++n)
      bf[n] = *(const short8*)&Bs[cur][n * 16 + (lane & 15)][(lane >> 4) * 8];
    #pragma unroll
    for (int m = 0; m < 4; ++m)
      af[m] = *(const short8*)&As[cur][wid * 64 + m * 16 + (lane & 15)][(lane >> 4) * 8];
    #pragma unroll
    for (int m = 0; m < 4; ++m)
      #pragma unroll
      for (int n = 0; n < 4; ++n)
        acc[m][n] = __builtin_amdgcn_mfma_f32_16x16x32_bf16(af[m], bf[n], acc[m][n], 0, 0, 0);
    if (more) E_STORE(cur ^ 1);
    __syncthreads();
    cur ^= 1;
  }
#undef E_LOAD
#undef E_STORE

  #pragma unroll
  for (int m = 0; m < 4; ++m) {
    #pragma unroll
    for (int j = 0; j < 4; ++j) {
      const int r = wid * 64 + m * 16 + ((lane >> 4) << 2) + j;
      if (m0 + r < ncnt) {
        const float sc = scs[r];
        const size_t ob = (size_t)toks[r] * DD + n0 + (lane & 15);
        #pragma unroll
        for (int n = 0; n < 4; ++n)
          sel[ob + n * 16] = acc[m][n][j] * sc;
      }
    }
  }
}

// ---------------- combine: lat_bf16[t][d] = sum_k sel[t*4+k][d] ----------------
__global__ __launch_bounds__(256) void k_combine(const float* __restrict__ sel,
                                                 unsigned short* __restrict__ lat)
{
  const size_t i = ((size_t)blockIdx.x * 256 + threadIdx.x) << 2;
  const size_t t = i >> 10, d = i & 1023;
  const float* p = sel + ((t << 2) << 10) + d;
  float4 s0 = *(const float4*)(p);
  float4 s1 = *(const float4*)(p + 1024);
  float4 s2 = *(const float4*)(p + 2048);
  float4 s3 = *(const float4*)(p + 3072);
  float r0 = s0.x + s1.x + s2.x + s3.x;
  float r1 = s0.y + s1.y + s2.y + s3.y;
  float r2 = s0.z + s1.z + s2.z + s3.z;
  float r3 = s0.w + s1.w + s2.w + s3.w;
  uint2 pk; pk.x = pack2(r0, r1); pk.y = pack2(r2, r3);
  *(uint2*)(lat + i) = pk;
}

// ---------------- out_proj: y = x + lat @ out_w^T + b  (BM=128,BN=64, reg-staged dbuf) ----------------
__global__ __launch_bounds__(256, 2) void k_outproj(
    const unsigned short* __restrict__ lat, const float* __restrict__ W2,
    const float* __restrict__ xres, const float* __restrict__ bias,
    float* __restrict__ y)
{
  const int n0 = blockIdx.x * 64;
  const int m0 = blockIdx.y * 128;
  const int tid = threadIdx.x, lane = tid & 63, wid = tid >> 6;

  __shared__ alignas(16) unsigned short As[2][128][40];
  __shared__ alignas(16) unsigned short Bs[2][64][40];

  const int aq = tid >> 2, aseg = tid & 3;
  const unsigned short* la0 = lat + (size_t)(m0 + aq) * DD + aseg * 8;
  const unsigned short* la1 = lat + (size_t)(m0 + aq + 64) * DD + aseg * 8;
  const int be = tid >> 2, bks = tid & 3;
  const float* wb = W2 + (size_t)(n0 + be) * DD + bks * 8;

  f32x4 acc[2][4];
  #pragma unroll
  for (int m = 0; m < 2; ++m)
    #pragma unroll
    for (int n = 0; n < 4; ++n)
      #pragma unroll
      for (int j = 0; j < 4; ++j) acc[m][n][j] = 0.f;

  int4 av0, av1;
  float4 w0, w1;

#define O_LOAD(kk) do { \
    av0 = *(const int4*)(la0 + (kk)); \
    av1 = *(const int4*)(la1 + (kk)); \
    w0 = *(const float4*)(wb + (kk)); \
    w1 = *(const float4*)(wb + (kk) + 4); \
  } while (0)

#define O_STORE(b) do { \
    *(int4*)&As[b][aq][aseg * 8]      = av0; \
    *(int4*)&As[b][aq + 64][aseg * 8] = av1; \
    uint4 pv; \
    pv.x = pack2(w0.x, w0.y); pv.y = pack2(w0.z, w0.w); \
    pv.z = pack2(w1.x, w1.y); pv.w = pack2(w1.z, w1.w); \
    *(uint4*)&Bs[b][be][bks * 8] = pv; \
  } while (0)

  O_LOAD(0); O_STORE(0); __syncthreads();
  int cur = 0;
  for (int t = 0; t < 32; ++t) {
    const bool more = (t < 31);
    if (more) O_LOAD((t + 1) * 32);
    short8 af[2], bf[4];
    #pragma unroll
    for (int n = 0; n < 4; ++n)
      bf[n] = *(const short8*)&Bs[cur][n * 16 + (lane & 15)][(lane >> 4) * 8];
    #pragma unroll
    for (int m = 0; m < 2; ++m)
      af[m] = *(const short8*)&As[cur][wid * 32 + m * 16 + (lane & 15)][(lane >> 4) * 8];
    #pragma unroll
    for (int m = 0; m < 2; ++m)
      #pragma unroll
      for (int n = 0; n < 4; ++n)
        acc[m][n] = __builtin_amdgcn_mfma_f32_16x16x32_bf16(af[m], bf[n], acc[m][n], 0, 0, 0);
    if (more) O_STORE(cur ^ 1);
    __syncthreads();
    cur ^= 1;
  }
#undef O_LOAD
#undef O_STORE

  #pragma unroll
  for (int m = 0; m < 2; ++m) {
    #pragma unroll
    for (int j = 0; j < 4; ++j) {
      const int t = m0 + wid * 32 + m * 16 + ((lane >> 4) << 2) + j;
      #pragma unroll
      for (int n = 0; n < 4; ++n) {
        const int e = n0 + n * 16 + (lane & 15);
        y[(size_t)t * DD + e] = xres[(size_t)t * DD + e] + acc[m][n][j] + bias[e];
      }
    }
  }
}

// ---------------- LayerNorm ----------------
__global__ __launch_bounds__(256) void k_ln(const float* __restrict__ y,
    const float* __restrict__ g, const float* __restrict__ b, float* __restrict__ out)
{
  const int t = blockIdx.x, tid = threadIdx.x;
  float4 v = *(const float4*)(y + (size_t)t * DD + tid * 4);
  float s  = v.x + v.y + v.z + v.w;
  float ss = v.x*v.x + v.y*v.y + v.z*v.z + v.w*v.w;
  #pragma unroll
  for (int off = 32; off; off >>= 1) { s += __shfl_down(s, off); ss += __shfl_down(ss, off); }
  __shared__ float rs[8];
  const int wid = tid >> 6, lane = tid & 63;
  if (lane == 0) { rs[wid] = s; rs[wid + 4] = ss; }
  __syncthreads();
  float S  = rs[0] + rs[1] + rs[2] + rs[3];
  float SS = rs[4] + rs[5] + rs[6] + rs[7];
  float mu = S * (1.0f / DD);
  float var = SS * (1.0f / DD) - mu * mu;
  float inv = rsqrtf(var + 1e-5f);
  float4 gg = *(const float4*)(g + tid * 4);
  float4 bb = *(const float4*)(b + tid * 4);
  float4 o;
  o.x = gg.x * (v.x - mu) * inv + bb.x;
  o.y = gg.y * (v.y - mu) * inv + bb.y;
  o.z = gg.z * (v.z - mu) * inv + bb.z;
  o.w = gg.w * (v.w - mu) * inv + bb.w;
  *(float4*)(out + (size_t)t * DD + tid * 4) = o;
}

extern "C" void kernel_launch(void* const* d_in, const int* in_sizes, int n_in,
                              void* d_out, int out_size, void* d_ws, size_t ws_size,
                              hipStream_t stream) {
  (void)in_sizes; (void)n_in; (void)out_size;
  const float* x   = (const float*)d_in[0];
  const float* gw  = (const float*)d_in[1];
  const float* lw  = (const float*)d_in[2];
  const float* ow  = (const float*)d_in[3];
  const float* obv = (const float*)d_in[4];
  const float* lng = (const float*)d_in[5];
  const float* lnb = (const float*)d_in[6];
  float* out = (float*)d_out;
  char* ws = (char*)d_ws;

  const size_t NEED_NEW = (133ull << 20);
  const size_t NEED_FB  = (48ull << 20) + 4096 + 2ull * LL * TT * 4;

  if (ws_size >= NEED_NEW) {
    // layout: [sel 32MB][xb 4MB][counts 4KB|btok 384KB|bscore 384KB -> 1MB][Wt 96MB]
    // Wt region reused after k_expert: [lat 4MB][y 8MB]
    float*          sel    = (float*)(ws);
    unsigned short* xb     = (unsigned short*)(ws + (32ull << 20));
    int*            counts = (int*)(ws + (36ull << 20));
    int*            btok   = (int*)(ws + (36ull << 20) + 4096);
    float*          bscore = (float*)(ws + (36ull << 20) + 4096 + (size_t)LL * TT * 4);
    unsigned short* Wt     = (unsigned short*)(ws + (37ull << 20));
    unsigned short* lat    = (unsigned short*)(ws + (37ull << 20));
    float*          y      = (float*)(ws + (41ull << 20));

    hipMemsetAsync(counts, 0, LL * sizeof(int), stream);
    k_gate<<<TT / 8, 256, 0, stream>>>(x, gw, xb, counts, btok, bscore);
    k_wconvT<<<dim3(8, 8, LL), 256, 0, stream>>>(lw, Wt);
    k_expert<<<dim3(8, 2, LL), 256, 0, stream>>>(xb, Wt, counts, btok, bscore, sel);
    k_combine<<<TT * DD / (256 * 4), 256, 0, stream>>>(sel, lat);
    k_outproj<<<dim3(16, 16), 256, 0, stream>>>(lat, ow, x, obv, y);
    k_ln<<<TT, 256, 0, stream>>>(y, lng, lnb, out);
  } else if (ws_size >= NEED_FB) {
    unsigned short* xb     = (unsigned short*)(ws);
    unsigned short* lat    = (unsigned short*)(ws + (4ull << 20));
    float*          y      = (float*)(ws + (8ull << 20));
    float*          sel    = (float*)(ws + (16ull << 20));
    int*            counts = (int*)(ws + (48ull << 20));
    int*            btok   = (int*)(ws + (48ull << 20) + 4096);
    float*          bscore = (float*)(ws + (48ull << 20) + 4096 + (size_t)LL * TT * 4);

    hipMemsetAsync(counts, 0, LL * sizeof(int), stream);
    k_gate<<<TT / 8, 256, 0, stream>>>(x, gw, xb, counts, btok, bscore);
    k_expert_fb<<<dim3(16, 2, LL), 256, 0, stream>>>(xb, lw, counts, btok, bscore, sel);
    k_combine<<<TT * DD / (256 * 4), 256, 0, stream>>>(sel, lat);
    k_outproj<<<dim3(16, 16), 256, 0, stream>>>(lat, ow, x, obv, y);
    k_ln<<<TT, 256, 0, stream>>>(y, lng, lnb, out);
  }
  // else: ws too small -> no safe path; leave output poisoned (loud failure)
}

// Round 5
// 212.691 us; speedup vs baseline: 1.1724x; 1.1724x over previous
//
#include <hip/hip_runtime.h>
#include <stdint.h>

// HyperLatticeBlock: B=2,S=1024,D=1024,L=48,K=4  (tokens T=2048)
// gate(top4)->bucketed single-pass expert GEMM (W fp32 staged, LDS-transposed)->combine->out_proj->LN
#define TT 2048
#define DD 1024
#define LL 48

typedef __attribute__((ext_vector_type(8))) short short8;
typedef __attribute__((ext_vector_type(4))) float f32x4;

static __device__ __forceinline__ unsigned int f2bf(float f) {
  union { float f; unsigned int u; } v; v.f = f;
  return (v.u + 0x7FFFu + ((v.u >> 16) & 1u)) >> 16;   // RNE f32->bf16 bits
}
static __device__ __forceinline__ unsigned int pack2(float a, float b) {
  return f2bf(a) | (f2bf(b) << 16);
}

typedef __attribute__((address_space(1))) const void* as1_t;
typedef __attribute__((address_space(3))) void* as3_t;
static __device__ __forceinline__ void gll16(const void* g, void* s) {
  __builtin_amdgcn_global_load_lds((as1_t)g, (as3_t)s, 16, 0, 0);
}

// ---------------- gate: logits fp32, top-4, softmax, bucket scatter, x->bf16 ----------------
__global__ __launch_bounds__(256) void k_gate(
    const float* __restrict__ x, const float* __restrict__ gw,
    unsigned short* __restrict__ xb,
    int* __restrict__ counts, int* __restrict__ btok, float* __restrict__ bscore)
{
  __shared__ float xs[8][1024];
  __shared__ float lg[8][48];
  const int tid = threadIdx.x;
  const int t0 = blockIdx.x * 8;
  for (int u = tid; u < 2048; u += 256) {
    int tok = u >> 8;
    int c = (u & 255) << 2;
    float4 v = *(const float4*)(x + (size_t)(t0 + tok) * DD + c);
    *(float4*)&xs[tok][c] = v;
    uint2 p; p.x = pack2(v.x, v.y); p.y = pack2(v.z, v.w);
    *(uint2*)(xb + (size_t)(t0 + tok) * DD + c) = p;
  }
  __syncthreads();
  const int lane = tid & 63, wid = tid >> 6;
  for (int li = 0; li < 12; ++li) {
    const int l = wid + (li << 2);
    const float4* gp = (const float4*)(gw + (size_t)l * DD);
    float4 g0 = gp[lane], g1 = gp[lane + 64], g2 = gp[lane + 128], g3 = gp[lane + 192];
    for (int tok = 0; tok < 8; ++tok) {
      const float4* xp = (const float4*)&xs[tok][0];
      float4 a0 = xp[lane], a1 = xp[lane + 64], a2 = xp[lane + 128], a3 = xp[lane + 192];
      float s = a0.x*g0.x + a0.y*g0.y + a0.z*g0.z + a0.w*g0.w
              + a1.x*g1.x + a1.y*g1.y + a1.z*g1.z + a1.w*g1.w
              + a2.x*g2.x + a2.y*g2.y + a2.z*g2.z + a2.w*g2.w
              + a3.x*g3.x + a3.y*g3.y + a3.z*g3.z + a3.w*g3.w;
      #pragma unroll
      for (int off = 32; off; off >>= 1) s += __shfl_down(s, off);
      if (lane == 0) lg[tok][l] = s;
    }
  }
  __syncthreads();
  if (tid < 8) {
    const int tok = tid;
    float v[4]; int id[4];
    unsigned long long taken = 0ull;
    for (int k = 0; k < 4; ++k) {
      float best = -3.4e38f; int bi = 0;
      for (int l = 0; l < 48; ++l) {
        float cand = lg[tok][l];
        if (!((taken >> l) & 1ull) && cand > best) { best = cand; bi = l; }
      }
      taken |= (1ull << bi); v[k] = best; id[k] = bi;
    }
    float e1 = expf(v[1] - v[0]);
    float e2 = expf(v[2] - v[0]);
    float e3 = expf(v[3] - v[0]);
    float inv = 1.0f / (1.0f + e1 + e2 + e3);
    float sc[4] = { inv, e1*inv, e2*inv, e3*inv };
    for (int k = 0; k < 4; ++k) {
      int pos = atomicAdd(&counts[id[k]], 1);
      btok[id[k] * TT + pos] = ((t0 + tok) << 2) | k;
      bscore[id[k] * TT + pos] = sc[k];
    }
  }
}

// ---------------- expert GEMM: single pass. BM=256, BN=128, BK=32, 8 waves ----------------
// OUT[t][e] = sum_d X[t][d] * W[l][d][e].
// A: gathered bf16 rows via gll -> LDS [256][32] (64B rows, frag b128 conflict-free).
// B: W fp32 via gll -> LDS [32][128] linear, source-column XOR-preswizzled;
//    transpose happens at frag build: 8x ds_read_b32 (stride 512B, 2-way after swizzle),
//    converted fp32->bf16 in registers.
__global__ __launch_bounds__(512, 4) void k_expert(
    const unsigned short* __restrict__ xb, const float* __restrict__ W,
    const int* __restrict__ counts, const int* __restrict__ btok,
    const float* __restrict__ bscore, float* __restrict__ sel)
{
  const int l = blockIdx.z;
  const int ncnt = counts[l];
  const int m0 = blockIdx.y * 256;
  if (m0 >= ncnt) return;
  const int n0 = blockIdx.x * 128;
  const int tid = threadIdx.x, lane = tid & 63, wid = tid >> 6;
  const int wr = wid & 3, wc = wid >> 2;         // 4 (m) x 2 (n) waves

  __shared__ alignas(16) unsigned short As[2][256 * 32];  // 16 KB each
  __shared__ alignas(16) float           Bs[2][32 * 128]; // 16 KB each
  __shared__ int   toks[256];
  __shared__ float scs[256];

  if (tid < 256) {
    int r = m0 + tid;
    toks[tid] = (r < ncnt) ? btok[l * TT + r] : 0;
    scs[tid]  = (r < ncnt) ? bscore[l * TT + r] : 0.f;
  }
  __syncthreads();

  // A staging: unit u = i*512+tid; row r=u>>2, 16B-col c=u&3
  const unsigned short* asrc0 = xb + (size_t)(toks[tid >> 2]       >> 2) * DD + (tid & 3) * 8;
  const unsigned short* asrc1 = xb + (size_t)(toks[128 + (tid >> 2)] >> 2) * DD + (tid & 3) * 8;
  // B staging: unit v = i*512+tid; d = v>>5, 16B-col cu = v&31; source col preswizzled; +n0 tile offset
  const float* Wl = W + (size_t)l * DD * DD + n0;
  const int d0 = tid >> 5, cu = tid & 31;
  const int d1 = d0 + 16;
  const float* bsrc0 = Wl + (size_t)d0 * DD + ((cu ^ (((d0 >> 3) & 1) << 2)) << 2);
  const float* bsrc1 = Wl + (size_t)d1 * DD + ((cu ^ (((d1 >> 3) & 1) << 2)) << 2);

  f32x4 acc[4][4];
  #pragma unroll
  for (int m = 0; m < 4; ++m)
    #pragma unroll
    for (int n = 0; n < 4; ++n)
      #pragma unroll
      for (int j = 0; j < 4; ++j) acc[m][n][j] = 0.f;

#define STAGE(buf, k0) do { \
    gll16(asrc0 + (k0), &As[buf][tid * 8]); \
    gll16(asrc1 + (k0), &As[buf][(512 + tid) * 8]); \
    gll16(bsrc0 + (size_t)(k0) * DD, &Bs[buf][tid * 4]); \
    gll16(bsrc1 + (size_t)(k0) * DD, &Bs[buf][(512 + tid) * 4]); \
  } while (0)

  const int fr = lane & 15, fq = lane >> 4;
  const int bkey = (fq & 1) << 4;                // read-side XOR (d>>3 == fq for d=fq*8+j)

  STAGE(0, 0);
  __syncthreads();
  int cur = 0;
  for (int t = 0; t < 32; ++t) {
    if (t < 31) STAGE(cur ^ 1, (t + 1) * 32);
    const unsigned short* Ab = As[cur];
    const float* Bb = Bs[cur];
    short8 af[4], bf[4];
    #pragma unroll
    for (int m = 0; m < 4; ++m)
      af[m] = *(const short8*)(Ab + (wr * 64 + m * 16 + fr) * 32 + fq * 8);
    #pragma unroll
    for (int n = 0; n < 4; ++n) {
      const float* bp = Bb + (size_t)fq * 8 * 128 + ((wc * 64 + n * 16 + fr) ^ bkey);
      float w0 = bp[0],       w1 = bp[128],     w2 = bp[256],     w3 = bp[384];
      float w4 = bp[512],     w5 = bp[640],     w6 = bp[768],     w7 = bp[896];
      uint4 pv;
      pv.x = pack2(w0, w1); pv.y = pack2(w2, w3);
      pv.z = pack2(w4, w5); pv.w = pack2(w6, w7);
      bf[n] = *(short8*)&pv;
    }
    #pragma unroll
    for (int m = 0; m < 4; ++m)
      #pragma unroll
      for (int n = 0; n < 4; ++n)
        acc[m][n] = __builtin_amdgcn_mfma_f32_16x16x32_bf16(af[m], bf[n], acc[m][n], 0, 0, 0);
    __syncthreads();
    cur ^= 1;
  }
#undef STAGE

  // epilogue: D[r][c]: c = lane&15 (e), r = (lane>>4)*4 + j  [m89-verified]
  #pragma unroll
  for (int m = 0; m < 4; ++m) {
    #pragma unroll
    for (int j = 0; j < 4; ++j) {
      const int r = wr * 64 + m * 16 + fq * 4 + j;
      if (m0 + r < ncnt) {
        const float sc = scs[r];
        const size_t ob = (size_t)toks[r] * DD + n0 + wc * 64 + fr;
        #pragma unroll
        for (int n = 0; n < 4; ++n)
          sel[ob + n * 16] = acc[m][n][j] * sc;
      }
    }
  }
}

// ---------------- combine: lat_bf16[t][d] = sum_k sel[t*4+k][d] ----------------
__global__ __launch_bounds__(256) void k_combine(const float* __restrict__ sel,
                                                 unsigned short* __restrict__ lat)
{
  const size_t i = ((size_t)blockIdx.x * 256 + threadIdx.x) << 2;
  const size_t t = i >> 10, d = i & 1023;
  const float* p = sel + ((t << 2) << 10) + d;
  float4 s0 = *(const float4*)(p);
  float4 s1 = *(const float4*)(p + 1024);
  float4 s2 = *(const float4*)(p + 2048);
  float4 s3 = *(const float4*)(p + 3072);
  float r0 = s0.x + s1.x + s2.x + s3.x;
  float r1 = s0.y + s1.y + s2.y + s3.y;
  float r2 = s0.z + s1.z + s2.z + s3.z;
  float r3 = s0.w + s1.w + s2.w + s3.w;
  uint2 pk; pk.x = pack2(r0, r1); pk.y = pack2(r2, r3);
  *(uint2*)(lat + i) = pk;
}

// ---------------- out_proj: y = x + lat @ out_w^T + b  (BM=128,BN=64, reg-staged dbuf) ----------------
__global__ __launch_bounds__(256, 2) void k_outproj(
    const unsigned short* __restrict__ lat, const float* __restrict__ W2,
    const float* __restrict__ xres, const float* __restrict__ bias,
    float* __restrict__ y)
{
  const int n0 = blockIdx.x * 64;
  const int m0 = blockIdx.y * 128;
  const int tid = threadIdx.x, lane = tid & 63, wid = tid >> 6;

  __shared__ alignas(16) unsigned short As[2][128][40];
  __shared__ alignas(16) unsigned short Bs[2][64][40];

  const int aq = tid >> 2, aseg = tid & 3;
  const unsigned short* la0 = lat + (size_t)(m0 + aq) * DD + aseg * 8;
  const unsigned short* la1 = lat + (size_t)(m0 + aq + 64) * DD + aseg * 8;
  const int be = tid >> 2, bks = tid & 3;
  const float* wb = W2 + (size_t)(n0 + be) * DD + bks * 8;

  f32x4 acc[2][4];
  #pragma unroll
  for (int m = 0; m < 2; ++m)
    #pragma unroll
    for (int n = 0; n < 4; ++n)
      #pragma unroll
      for (int j = 0; j < 4; ++j) acc[m][n][j] = 0.f;

  int4 av0, av1;
  float4 w0, w1;

#define O_LOAD(kk) do { \
    av0 = *(const int4*)(la0 + (kk)); \
    av1 = *(const int4*)(la1 + (kk)); \
    w0 = *(const float4*)(wb + (kk)); \
    w1 = *(const float4*)(wb + (kk) + 4); \
  } while (0)

#define O_STORE(b) do { \
    *(int4*)&As[b][aq][aseg * 8]      = av0; \
    *(int4*)&As[b][aq + 64][aseg * 8] = av1; \
    uint4 pv; \
    pv.x = pack2(w0.x, w0.y); pv.y = pack2(w0.z, w0.w); \
    pv.z = pack2(w1.x, w1.y); pv.w = pack2(w1.z, w1.w); \
    *(uint4*)&Bs[b][be][bks * 8] = pv; \
  } while (0)

  O_LOAD(0); O_STORE(0); __syncthreads();
  int cur = 0;
  for (int t = 0; t < 32; ++t) {
    const bool more = (t < 31);
    if (more) O_LOAD((t + 1) * 32);
    short8 af[2], bf[4];
    #pragma unroll
    for (int n = 0; n < 4; ++n)
      bf[n] = *(const short8*)&Bs[cur][n * 16 + (lane & 15)][(lane >> 4) * 8];
    #pragma unroll
    for (int m = 0; m < 2; ++m)
      af[m] = *(const short8*)&As[cur][wid * 32 + m * 16 + (lane & 15)][(lane >> 4) * 8];
    #pragma unroll
    for (int m = 0; m < 2; ++m)
      #pragma unroll
      for (int n = 0; n < 4; ++n)
        acc[m][n] = __builtin_amdgcn_mfma_f32_16x16x32_bf16(af[m], bf[n], acc[m][n], 0, 0, 0);
    if (more) O_STORE(cur ^ 1);
    __syncthreads();
    cur ^= 1;
  }
#undef O_LOAD
#undef O_STORE

  #pragma unroll
  for (int m = 0; m < 2; ++m) {
    #pragma unroll
    for (int j = 0; j < 4; ++j) {
      const int t = m0 + wid * 32 + m * 16 + ((lane >> 4) << 2) + j;
      #pragma unroll
      for (int n = 0; n < 4; ++n) {
        const int e = n0 + n * 16 + (lane & 15);
        y[(size_t)t * DD + e] = xres[(size_t)t * DD + e] + acc[m][n][j] + bias[e];
      }
    }
  }
}

// ---------------- LayerNorm ----------------
__global__ __launch_bounds__(256) void k_ln(const float* __restrict__ y,
    const float* __restrict__ g, const float* __restrict__ b, float* __restrict__ out)
{
  const int t = blockIdx.x, tid = threadIdx.x;
  float4 v = *(const float4*)(y + (size_t)t * DD + tid * 4);
  float s  = v.x + v.y + v.z + v.w;
  float ss = v.x*v.x + v.y*v.y + v.z*v.z + v.w*v.w;
  #pragma unroll
  for (int off = 32; off; off >>= 1) { s += __shfl_down(s, off); ss += __shfl_down(ss, off); }
  __shared__ float rs[8];
  const int wid = tid >> 6, lane = tid & 63;
  if (lane == 0) { rs[wid] = s; rs[wid + 4] = ss; }
  __syncthreads();
  float S  = rs[0] + rs[1] + rs[2] + rs[3];
  float SS = rs[4] + rs[5] + rs[6] + rs[7];
  float mu = S * (1.0f / DD);
  float var = SS * (1.0f / DD) - mu * mu;
  float inv = rsqrtf(var + 1e-5f);
  float4 gg = *(const float4*)(g + tid * 4);
  float4 bb = *(const float4*)(b + tid * 4);
  float4 o;
  o.x = gg.x * (v.x - mu) * inv + bb.x;
  o.y = gg.y * (v.y - mu) * inv + bb.y;
  o.z = gg.z * (v.z - mu) * inv + bb.z;
  o.w = gg.w * (v.w - mu) * inv + bb.w;
  *(float4*)(out + (size_t)t * DD + tid * 4) = o;
}

extern "C" void kernel_launch(void* const* d_in, const int* in_sizes, int n_in,
                              void* d_out, int out_size, void* d_ws, size_t ws_size,
                              hipStream_t stream) {
  (void)in_sizes; (void)n_in; (void)out_size;
  const float* x   = (const float*)d_in[0];
  const float* gw  = (const float*)d_in[1];
  const float* lw  = (const float*)d_in[2];
  const float* ow  = (const float*)d_in[3];
  const float* obv = (const float*)d_in[4];
  const float* lng = (const float*)d_in[5];
  const float* lnb = (const float*)d_in[6];
  float* out = (float*)d_out;
  char* ws = (char*)d_ws;

  unsigned short* xb     = (unsigned short*)(ws);                          // 4 MB
  unsigned short* lat    = (unsigned short*)(ws + (4ull << 20));           // 4 MB
  float*          y      = (float*)(ws + (8ull << 20));                    // 8 MB
  float*          sel    = (float*)(ws + (16ull << 20));                   // 32 MB
  int*            counts = (int*)(ws + (48ull << 20));                     // 192 B
  int*            btok   = (int*)(ws + (48ull << 20) + 4096);              // 384 KB
  float*          bscore = (float*)(ws + (48ull << 20) + 4096 + (size_t)LL * TT * 4); // 384 KB
  if (ws_size < ((48ull << 20) + 4096 + 2ull * LL * TT * 4)) return;       // loud failure

  hipMemsetAsync(counts, 0, LL * sizeof(int), stream);
  k_gate<<<TT / 8, 256, 0, stream>>>(x, gw, xb, counts, btok, bscore);
  k_expert<<<dim3(8, 2, LL), 512, 0, stream>>>(xb, lw, counts, btok, bscore, sel);
  k_combine<<<TT * DD / (256 * 4), 256, 0, stream>>>(sel, lat);
  k_outproj<<<dim3(16, 16), 256, 0, stream>>>(lat, ow, x, obv, y);
  k_ln<<<TT, 256, 0, stream>>>(y, lng, lnb, out);
}